// Round 13
// baseline (175.076 us; speedup 1.0000x reference)
//
#include <hip/hip_runtime.h>
#include <hip/hip_fp16.h>

#define N_NODES 50000
#define N_EDGES 600000
#define HDIM 128
#define EPS 1e-5f
#define ELLW 64
#define LPADH 136   // fp16 pad: row stride 272B = 17x16B (aligned b128, 8-bank spread)

typedef __attribute__((ext_vector_type(4))) float f32x4;
typedef __attribute__((ext_vector_type(4))) _Float16 h16x4;
typedef __attribute__((ext_vector_type(8))) _Float16 h16x8;

#define EDGE_BLKS ((N_EDGES + 255) / 256)    // 2344, FIRST in grid
#define GEMM0_BLKS ((N_NODES + 63) / 64)     // 782: X@W0 in the edge phase's shadow
#define PACK_BLKS 24                         // 3 weights (W1,W2,hW1) x 8 blocks

// ---------------- detect edge dtype + zero deg (one kernel) ----------------
__global__ void detect_zero(const int* __restrict__ ei, int* __restrict__ flag,
                            int* __restrict__ deg) {
    int i = blockIdx.x * 256 + threadIdx.x;
    if (i < N_NODES) deg[i] = 0;
    if (blockIdx.x == 0) {
        __shared__ int nonzero;
        if (threadIdx.x == 0) nonzero = 0;
        __syncthreads();
        int acc = 0;
        for (int k = threadIdx.x; k < 1024; k += 256)
            acc |= ei[2 * k + 1];
        if (acc) atomicOr(&nonzero, 1);
        __syncthreads();
        if (threadIdx.x == 0) *flag = (nonzero == 0) ? 1 : 0;
    }
}

__device__ __forceinline__ int load_idx(const int* __restrict__ ei, int pos, int f) {
    return f ? ei[2 * pos] : ei[pos];
}

// ---------------- f16 hi/lo split ----------------
__device__ __forceinline__ void hsplit(float a, _Float16& hi, _Float16& lo) {
    _Float16 h = (_Float16)a;           // RNE
    hi = h;
    lo = (_Float16)(a - (float)h);
}

// ---------------- fused prep: edge->ELL | gemm0 (X@W0 -> y0 fp16) | pack_w ----------------
__global__ void prep_kernel(const float* __restrict__ x,
                            const int* __restrict__ ei, const int* __restrict__ flag,
                            int* __restrict__ deg, unsigned short* __restrict__ ell,
                            const float* __restrict__ W0, _Float16* __restrict__ y0,
                            const float* __restrict__ W1, const float* __restrict__ W2,
                            const float* __restrict__ W3,
                            _Float16* __restrict__ pkh, _Float16* __restrict__ pkl) {
    int b = blockIdx.x;
    if (b < EDGE_BLKS) {
        // edge phase: dispatched first; gemm0/pack blocks fill in behind
        int e = b * 256 + threadIdx.x;
        if (e < N_EDGES) {
            int f = *flag;
            int s = load_idx(ei, e, f);
            int d = load_idx(ei, N_EDGES + e, f);
            int pos = atomicAdd(&deg[d], 1);
            if (pos < ELLW) ell[(size_t)d * ELLW + pos] = (unsigned short)s;
        }
    } else if (b < EDGE_BLKS + GEMM0_BLKS) {
        // GEMM0: y0 = fp16(X @ W0), W0 fragments read from global (L2-hot)
        int gb = b - EDGE_BLKS;
        int t = threadIdx.x;
        int wave = t >> 6, lane = t & 63;
        int lrow = lane & 15, lk = lane >> 4;
        int rowb = gb * 64 + wave * 16;
        int arowi = rowb + lrow;
        f32x4 acc[8];
#pragma unroll
        for (int cf = 0; cf < 8; ++cf) acc[cf] = (f32x4){0.f, 0.f, 0.f, 0.f};
        const float* arow = x + (size_t)arowi * HDIM;
        bool aok = arowi < N_NODES;
#pragma unroll
        for (int ks = 0; ks < 4; ++ks) {
            h16x8 a;
            if (aok) {
                float4 a0 = *(const float4*)(arow + ks * 32 + lk * 8);
                float4 a1 = *(const float4*)(arow + ks * 32 + lk * 8 + 4);
                a[0] = (_Float16)a0.x; a[1] = (_Float16)a0.y;
                a[2] = (_Float16)a0.z; a[3] = (_Float16)a0.w;
                a[4] = (_Float16)a1.x; a[5] = (_Float16)a1.y;
                a[6] = (_Float16)a1.z; a[7] = (_Float16)a1.w;
            } else {
#pragma unroll
                for (int i = 0; i < 8; ++i) a[i] = (_Float16)0.f;
            }
            int k0 = ks * 32 + lk * 8;
#pragma unroll
            for (int cf = 0; cf < 8; ++cf) {
                int col = cf * 16 + lrow;
                h16x8 bh, bl;
#pragma unroll
                for (int i = 0; i < 8; ++i) {
                    _Float16 hh, ll;
                    hsplit(W0[(size_t)(k0 + i) * HDIM + col], hh, ll);
                    bh[i] = hh; bl[i] = ll;
                }
                acc[cf] = __builtin_amdgcn_mfma_f32_16x16x32_f16(a, bh, acc[cf], 0, 0, 0);
                acc[cf] = __builtin_amdgcn_mfma_f32_16x16x32_f16(a, bl, acc[cf], 0, 0, 0);
            }
        }
#pragma unroll
        for (int r = 0; r < 4; ++r) {
            int row = rowb + lk * 4 + r;
            if (row < N_NODES) {
#pragma unroll
                for (int cf = 0; cf < 8; ++cf)
                    y0[(size_t)row * HDIM + cf * 16 + lrow] = (_Float16)acc[cf][r];
            }
        }
    } else {
        int pb = b - EDGE_BLKS - GEMM0_BLKS;   // 0..23
        int wsel = pb >> 3;                    // 0:W1 1:W2 2:hW1
        const float* W = (wsel == 0) ? W1 : (wsel == 1) ? W2 : W3;
        int idx = (pb & 7) * 256 + threadIdx.x; // 0..2047
        int lane = idx & 63;
        int cf = (idx >> 6) & 7;
        int ks = idx >> 9;
        int col = cf * 16 + (lane & 15);
        int k0 = ks * 32 + (lane >> 4) * 8;
        _Float16 h[8], l[8];
#pragma unroll
        for (int i = 0; i < 8; ++i) hsplit(W[(size_t)(k0 + i) * HDIM + col], h[i], l[i]);
        size_t base = (size_t)wsel * 16384 + (size_t)idx * 8;
#pragma unroll
        for (int i = 0; i < 8; ++i) { pkh[base + i] = h[i]; pkl[base + i] = l[i]; }
    }
}

// ---------------- layer 0: ELL-aggregate y0 + bias + LN + ReLU (no GEMM) ----------------
__global__ __launch_bounds__(256) void agg_ln(const _Float16* __restrict__ y0,
                                              const int* __restrict__ deg,
                                              const unsigned short* __restrict__ ell,
                                              const float* __restrict__ bias,
                                              const float* __restrict__ gamma,
                                              const float* __restrict__ beta,
                                              _Float16* __restrict__ out) {
    int node = blockIdx.x * 16 + (threadIdx.x >> 4);
    int sub = threadIdx.x & 15;
    if (node >= N_NODES) return;
    const h16x8* h8 = (const h16x8*)y0;
    int dn = deg[node];
    float dd = rsqrtf((float)dn + 1.0f);
    h16x8 v = h8[(size_t)node * 16 + sub];
    float acc[8];
#pragma unroll
    for (int i = 0; i < 8; ++i) acc[i] = dd * (float)v[i]; // self (×dd below)
    int cnt = min(dn, ELLW);
    const unsigned short* row = ell + (size_t)node * ELLW;
    for (int j = 0; j < cnt; j += 4) {
        uint2 pk = *(const uint2*)(row + j);
        int s0 = (int)(pk.x & 0xFFFFu);
        int s1 = (int)(pk.x >> 16);
        int s2 = (int)(pk.y & 0xFFFFu);
        int s3 = (int)(pk.y >> 16);
        bool k1 = j + 1 < cnt, k2 = j + 2 < cnt, k3 = j + 3 < cnt;
        s1 = k1 ? s1 : s0;
        s2 = k2 ? s2 : s0;
        s3 = k3 ? s3 : s0;
        int d0 = deg[s0];
        int d1 = deg[s1];
        int d2 = deg[s2];
        int d3 = deg[s3];
        h16x8 u0 = h8[(size_t)s0 * 16 + sub];
        h16x8 u1 = h8[(size_t)s1 * 16 + sub];
        h16x8 u2 = h8[(size_t)s2 * 16 + sub];
        h16x8 u3 = h8[(size_t)s3 * 16 + sub];
        float w0 = rsqrtf((float)d0 + 1.0f);
        float w1 = k1 ? rsqrtf((float)d1 + 1.0f) : 0.f;
        float w2 = k2 ? rsqrtf((float)d2 + 1.0f) : 0.f;
        float w3 = k3 ? rsqrtf((float)d3 + 1.0f) : 0.f;
#pragma unroll
        for (int i = 0; i < 8; ++i) {
            acc[i] += w0 * (float)u0[i];
            acc[i] += w1 * (float)u1[i];
            acc[i] += w2 * (float)u2[i];
            acc[i] += w3 * (float)u3[i];
        }
    }
    // bias + two-pass LN over the 128-wide row (16 lanes x 8) + ReLU
    float4 bi0 = *(const float4*)&bias[sub * 8];
    float4 bi1 = *(const float4*)&bias[sub * 8 + 4];
    float bv[8] = {bi0.x, bi0.y, bi0.z, bi0.w, bi1.x, bi1.y, bi1.z, bi1.w};
    float vv[8];
    float s1v = 0.f;
#pragma unroll
    for (int i = 0; i < 8; ++i) {
        vv[i] = acc[i] * dd + bv[i];
        s1v += vv[i];
    }
#pragma unroll
    for (int m = 1; m <= 8; m <<= 1) s1v += __shfl_xor(s1v, m);
    float mean = s1v * (1.0f / 128.0f);
    float s2v = 0.f;
    float cc[8];
#pragma unroll
    for (int i = 0; i < 8; ++i) {
        cc[i] = vv[i] - mean;
        s2v += cc[i] * cc[i];
    }
#pragma unroll
    for (int m = 1; m <= 8; m <<= 1) s2v += __shfl_xor(s2v, m);
    float rs = rsqrtf(s2v * (1.0f / 128.0f) + EPS);
    float4 g0 = *(const float4*)&gamma[sub * 8];
    float4 g1 = *(const float4*)&gamma[sub * 8 + 4];
    float4 e0 = *(const float4*)&beta[sub * 8];
    float4 e1 = *(const float4*)&beta[sub * 8 + 4];
    float gv[8] = {g0.x, g0.y, g0.z, g0.w, g1.x, g1.y, g1.z, g1.w};
    float ev[8] = {e0.x, e0.y, e0.z, e0.w, e1.x, e1.y, e1.z, e1.w};
    h16x8 r;
#pragma unroll
    for (int i = 0; i < 8; ++i) {
        float y = cc[i] * rs * gv[i] + ev[i];
        r[i] = (_Float16)(y > 0.f ? y : 0.f);
    }
    ((h16x8*)out)[(size_t)node * 16 + sub] = r;
}

// ---------------- fused layer (1,2): ELL-aggregate -> LDS fp16 -> MFMA -> LN -> ReLU ----------------
__global__ __launch_bounds__(256) void layer_fused(const _Float16* __restrict__ h,
                                                   const int* __restrict__ deg,
                                                   const unsigned short* __restrict__ ell,
                                                   const _Float16* __restrict__ Bh,
                                                   const _Float16* __restrict__ Bl,
                                                   const float* __restrict__ bias,
                                                   const float* __restrict__ gamma,
                                                   const float* __restrict__ beta,
                                                   _Float16* __restrict__ out, int nrows) {
    __shared__ _Float16 As[64][LPADH]; // 17.4 KB
    int t = threadIdx.x;
    int blockRow = blockIdx.x * 64;

    {
        int g = t >> 4, sub = t & 15;
        const h16x8* h8 = (const h16x8*)h;
        for (int j = 0; j < 4; ++j) {
            int rl = j * 16 + g;
            int node = blockRow + rl;
            h16x8 r;
            if (node < nrows) {
                int dn = deg[node];
                float dd = rsqrtf((float)dn + 1.0f);
                h16x8 v = h8[(size_t)node * 16 + sub];
                float acc[8];
#pragma unroll
                for (int i = 0; i < 8; ++i) acc[i] = dd * (float)v[i];
                int cnt = min(dn, ELLW);
                const unsigned short* row = ell + (size_t)node * ELLW;
                for (int e = 0; e < cnt; e += 4) {
                    uint2 pk = *(const uint2*)(row + e);
                    int s0 = (int)(pk.x & 0xFFFFu);
                    int s1 = (int)(pk.x >> 16);
                    int s2 = (int)(pk.y & 0xFFFFu);
                    int s3 = (int)(pk.y >> 16);
                    bool k1 = e + 1 < cnt, k2 = e + 2 < cnt, k3 = e + 3 < cnt;
                    s1 = k1 ? s1 : s0;
                    s2 = k2 ? s2 : s0;
                    s3 = k3 ? s3 : s0;
                    int d0 = deg[s0];
                    int d1 = deg[s1];
                    int d2 = deg[s2];
                    int d3 = deg[s3];
                    h16x8 u0 = h8[(size_t)s0 * 16 + sub];
                    h16x8 u1 = h8[(size_t)s1 * 16 + sub];
                    h16x8 u2 = h8[(size_t)s2 * 16 + sub];
                    h16x8 u3 = h8[(size_t)s3 * 16 + sub];
                    float w0 = rsqrtf((float)d0 + 1.0f);
                    float w1 = k1 ? rsqrtf((float)d1 + 1.0f) : 0.f;
                    float w2 = k2 ? rsqrtf((float)d2 + 1.0f) : 0.f;
                    float w3 = k3 ? rsqrtf((float)d3 + 1.0f) : 0.f;
#pragma unroll
                    for (int i = 0; i < 8; ++i) {
                        acc[i] += w0 * (float)u0[i];
                        acc[i] += w1 * (float)u1[i];
                        acc[i] += w2 * (float)u2[i];
                        acc[i] += w3 * (float)u3[i];
                    }
                }
#pragma unroll
                for (int i = 0; i < 8; ++i) r[i] = (_Float16)(acc[i] * dd);
            } else {
#pragma unroll
                for (int i = 0; i < 8; ++i) r[i] = (_Float16)0.f;
            }
            *(h16x8*)&As[rl][sub * 8] = r;
        }
    }
    __syncthreads();

    int wave = t >> 6, lane = t & 63;
    int lrow = lane & 15, lk = lane >> 4;
    int rowb = blockRow + wave * 16;

    f32x4 acc[8];
#pragma unroll
    for (int cf = 0; cf < 8; ++cf) acc[cf] = (f32x4){0.f, 0.f, 0.f, 0.f};

#pragma unroll
    for (int ks = 0; ks < 4; ++ks) {
        h16x8 a = *(const h16x8*)&As[wave * 16 + lrow][ks * 32 + lk * 8];
        const _Float16* bhp = Bh + (size_t)(ks * 8) * 512 + (size_t)lane * 8;
        const _Float16* blp = Bl + (size_t)(ks * 8) * 512 + (size_t)lane * 8;
#pragma unroll
        for (int cf = 0; cf < 8; ++cf) {
            h16x8 bh = *(const h16x8*)(bhp + (size_t)cf * 512);
            h16x8 bl = *(const h16x8*)(blp + (size_t)cf * 512);
            acc[cf] = __builtin_amdgcn_mfma_f32_16x16x32_f16(a, bh, acc[cf], 0, 0, 0);
            acc[cf] = __builtin_amdgcn_mfma_f32_16x16x32_f16(a, bl, acc[cf], 0, 0, 0);
        }
    }

    float bias_v[8], gam[8], bet[8];
#pragma unroll
    for (int cf = 0; cf < 8; ++cf) {
        bias_v[cf] = bias[cf * 16 + lrow];
        gam[cf] = gamma[cf * 16 + lrow];
        bet[cf] = beta[cf * 16 + lrow];
    }
#pragma unroll
    for (int r = 0; r < 4; ++r) {
        float vv[8];
        float s1 = 0.f;
#pragma unroll
        for (int cf = 0; cf < 8; ++cf) {
            vv[cf] = acc[cf][r] + bias_v[cf];
            s1 += vv[cf];
        }
#pragma unroll
        for (int m = 1; m <= 8; m <<= 1) s1 += __shfl_xor(s1, m);
        float mean = s1 * (1.0f / 128.0f);
        float s2 = 0.f;
        float cc[8];
#pragma unroll
        for (int cf = 0; cf < 8; ++cf) {
            cc[cf] = vv[cf] - mean;
            s2 += cc[cf] * cc[cf];
        }
#pragma unroll
        for (int m = 1; m <= 8; m <<= 1) s2 += __shfl_xor(s2, m);
        float rs = rsqrtf(s2 * (1.0f / 128.0f) + EPS);
        int row = rowb + lk * 4 + r;
        if (row < nrows) {
#pragma unroll
            for (int cf = 0; cf < 8; ++cf) {
                float y = cc[cf] * rs * gam[cf] + bet[cf];
                out[(size_t)row * HDIM + cf * 16 + lrow] = (_Float16)(y > 0.f ? y : 0.f);
            }
        }
    }
}

// ---------------- head: logits = ReLU(A@hW1+hb1)@hW2 + hb2 ----------------
__global__ __launch_bounds__(256) void head_mfma(const _Float16* __restrict__ A,
                                                 const _Float16* __restrict__ Bh,
                                                 const _Float16* __restrict__ Bl,
                                                 const float* __restrict__ bias,
                                                 const float* __restrict__ w2,
                                                 const float* __restrict__ b2p,
                                                 float* __restrict__ out, int nrows) {
    int t = threadIdx.x;
    int wave = t >> 6, lane = t & 63;
    int lrow = lane & 15, lk = lane >> 4;
    int rowb = blockIdx.x * 64 + wave * 16;

    f32x4 acc[8];
#pragma unroll
    for (int cf = 0; cf < 8; ++cf) acc[cf] = (f32x4){0.f, 0.f, 0.f, 0.f};

    const _Float16* arow = A + (size_t)(rowb + lrow) * HDIM;
#pragma unroll
    for (int ks = 0; ks < 4; ++ks) {
        h16x8 a = *(const h16x8*)(arow + ks * 32 + lk * 8);
        const _Float16* bhp = Bh + (size_t)(ks * 8) * 512 + (size_t)lane * 8;
        const _Float16* blp = Bl + (size_t)(ks * 8) * 512 + (size_t)lane * 8;
#pragma unroll
        for (int cf = 0; cf < 8; ++cf) {
            h16x8 bh = *(const h16x8*)(bhp + (size_t)cf * 512);
            h16x8 bl = *(const h16x8*)(blp + (size_t)cf * 512);
            acc[cf] = __builtin_amdgcn_mfma_f32_16x16x32_f16(a, bh, acc[cf], 0, 0, 0);
            acc[cf] = __builtin_amdgcn_mfma_f32_16x16x32_f16(a, bl, acc[cf], 0, 0, 0);
        }
    }

    float bias_v[8], w2v[8];
#pragma unroll
    for (int cf = 0; cf < 8; ++cf) {
        bias_v[cf] = bias[cf * 16 + lrow];
        w2v[cf] = w2[cf * 16 + lrow];
    }
    float b2 = b2p[0];
#pragma unroll
    for (int r = 0; r < 4; ++r) {
        float part = 0.f;
#pragma unroll
        for (int cf = 0; cf < 8; ++cf) {
            float y = acc[cf][r] + bias_v[cf];
            y = y > 0.f ? y : 0.f;
            part += y * w2v[cf];
        }
#pragma unroll
        for (int m = 1; m <= 8; m <<= 1) part += __shfl_xor(part, m);
        int row = rowb + lk * 4 + r;
        if (row < nrows && lrow == 0) out[row] = part + b2;
    }
}

extern "C" void kernel_launch(void* const* d_in, const int* in_sizes, int n_in,
                              void* d_out, int out_size, void* d_ws, size_t ws_size,
                              hipStream_t stream) {
    (void)in_sizes; (void)n_in; (void)out_size; (void)ws_size;
    const float* x   = (const float*)d_in[0];
    const int*   ei  = (const int*)d_in[1];
    const float* W0  = (const float*)d_in[2];
    const float* b0  = (const float*)d_in[3];
    const float* g0  = (const float*)d_in[4];
    const float* be0 = (const float*)d_in[5];
    const float* W1  = (const float*)d_in[6];
    const float* b1  = (const float*)d_in[7];
    const float* g1  = (const float*)d_in[8];
    const float* be1 = (const float*)d_in[9];
    const float* W2  = (const float*)d_in[10];
    const float* b2  = (const float*)d_in[11];
    const float* g2  = (const float*)d_in[12];
    const float* be2 = (const float*)d_in[13];
    const float* hW1 = (const float*)d_in[14];
    const float* hb1 = (const float*)d_in[15];
    const float* hW2 = (const float*)d_in[16];
    const float* hb2 = (const float*)d_in[17];
    float* out = (float*)d_out;

    char* w = (char*)d_ws;
    size_t off = 0;
    auto alloc = [&](size_t bytes) -> void* {
        void* p = w + off;
        off += (bytes + 255) & ~(size_t)255;
        return p;
    };
    int*            deg  = (int*)alloc((size_t)N_NODES * 4);
    unsigned short* ell  = (unsigned short*)alloc((size_t)N_NODES * ELLW * 2);
    int*            flag = (int*)alloc(256);
    _Float16*       y0   = (_Float16*)alloc((size_t)N_NODES * HDIM * 2);
    _Float16*       hA   = (_Float16*)alloc((size_t)N_NODES * HDIM * 2);
    _Float16*       hB   = (_Float16*)alloc((size_t)N_NODES * HDIM * 2);
    _Float16*       pkh  = (_Float16*)alloc((size_t)3 * 16384 * 2);
    _Float16*       pkl  = (_Float16*)alloc((size_t)3 * 16384 * 2);

    detect_zero<<<(N_NODES + 255) / 256, 256, 0, stream>>>(ei, flag, deg);
    prep_kernel<<<EDGE_BLKS + GEMM0_BLKS + PACK_BLKS, 256, 0, stream>>>(
        x, ei, flag, deg, ell, W0, y0, W1, W2, hW1, pkh, pkl);

    int nab = (N_NODES + 15) / 16; // 3125
    int ngb = (N_NODES + 63) / 64; // 782
    // layer 0: agg(y0) + b0 + LN + ReLU -> hA   (GEMM already done in prep)
    agg_ln<<<nab, 256, 0, stream>>>(y0, deg, ell, b0, g0, be0, hA);
    // layer 1: hA -> hB  (W1 = pkh+0)
    layer_fused<<<ngb, 256, 0, stream>>>(hA, deg, ell, pkh, pkl, b1, g1, be1, hB, N_NODES);
    // layer 2: hB -> hA  (W2 = pkh+16384)
    layer_fused<<<ngb, 256, 0, stream>>>(hB, deg, ell, pkh + (size_t)16384, pkl + (size_t)16384,
                                         b2, g2, be2, hA, N_NODES);
    // head: ReLU(hA @ hW1 + hb1) @ hW2 + hb2 -> logits  (hW1 = pkh+32768)
    head_mfma<<<ngb, 256, 0, stream>>>(hA, pkh + (size_t)2 * 16384, pkl + (size_t)2 * 16384,
                                       hb1, hW2, hb2, out, N_NODES);
}

// Round 14
// 169.005 us; speedup vs baseline: 1.0359x; 1.0359x over previous
//
#include <hip/hip_runtime.h>
#include <hip/hip_fp16.h>

#define N_NODES 50000
#define N_EDGES 600000
#define HDIM 128
#define EPS 1e-5f
#define ELLW 64
#define LPADH 136   // fp16 pad: row stride 272B = 17x16B (aligned b128, 8-bank spread)

typedef __attribute__((ext_vector_type(4))) float f32x4;
typedef __attribute__((ext_vector_type(4))) _Float16 h16x4;
typedef __attribute__((ext_vector_type(8))) _Float16 h16x8;

#define EDGE_BLKS ((N_EDGES + 255) / 256)    // 2344, FIRST in grid
#define CVT_BLKS 6250                        // N_NODES*32 float4 / 256
#define PACK_BLKS 32                         // 4 weights x 8 blocks

// ---------------- detect edge dtype + zero deg (one kernel) ----------------
__global__ void detect_zero(const int* __restrict__ ei, int* __restrict__ flag,
                            int* __restrict__ deg) {
    int i = blockIdx.x * 256 + threadIdx.x;
    if (i < N_NODES) deg[i] = 0;
    if (blockIdx.x == 0) {
        __shared__ int nonzero;
        if (threadIdx.x == 0) nonzero = 0;
        __syncthreads();
        int acc = 0;
        for (int k = threadIdx.x; k < 1024; k += 256)
            acc |= ei[2 * k + 1];
        if (acc) atomicOr(&nonzero, 1);
        __syncthreads();
        if (threadIdx.x == 0) *flag = (nonzero == 0) ? 1 : 0;
    }
}

__device__ __forceinline__ int load_idx(const int* __restrict__ ei, int pos, int f) {
    return f ? ei[2 * pos] : ei[pos];
}

// ---------------- f16 hi/lo split ----------------
__device__ __forceinline__ void hsplit(float a, _Float16& hi, _Float16& lo) {
    _Float16 h = (_Float16)a;           // RNE
    hi = h;
    lo = (_Float16)(a - (float)h);
}

// ---------------- fused prep: edge->ELL (first, low-VGPR) | cvt_x | pack_w ----------------
// NOTE: keep ALL branches register-light — kernel-wide VGPR max gates the
// latency-bound edge phase's occupancy (R13 lesson: 48 VGPR -> -3 us total).
__global__ void prep_kernel(const float* __restrict__ x, _Float16* __restrict__ xh,
                            const int* __restrict__ ei, const int* __restrict__ flag,
                            int* __restrict__ deg, unsigned short* __restrict__ ell,
                            const float* __restrict__ W0, const float* __restrict__ W1,
                            const float* __restrict__ W2, const float* __restrict__ W3,
                            _Float16* __restrict__ pkh, _Float16* __restrict__ pkl) {
    int b = blockIdx.x;
    if (b < EDGE_BLKS) {
        int e = b * 256 + threadIdx.x;
        if (e < N_EDGES) {
            int f = *flag;
            int s = load_idx(ei, e, f);
            int d = load_idx(ei, N_EDGES + e, f);
            int pos = atomicAdd(&deg[d], 1);
            if (pos < ELLW) ell[(size_t)d * ELLW + pos] = (unsigned short)s;
        }
    } else if (b < EDGE_BLKS + CVT_BLKS) {
        int idx = (b - EDGE_BLKS) * 256 + threadIdx.x;
        if (idx < N_NODES * 32) {
            float4 v = ((const float4*)x)[idx];
            h16x4 o;
            o[0] = (_Float16)v.x; o[1] = (_Float16)v.y;
            o[2] = (_Float16)v.z; o[3] = (_Float16)v.w;
            ((h16x4*)xh)[idx] = o;
        }
    } else {
        int pb = b - EDGE_BLKS - CVT_BLKS;   // 0..31
        int wsel = pb >> 3;
        const float* W = (wsel == 0) ? W0 : (wsel == 1) ? W1 : (wsel == 2) ? W2 : W3;
        int idx = (pb & 7) * 256 + threadIdx.x; // 0..2047
        int lane = idx & 63;
        int cf = (idx >> 6) & 7;
        int ks = idx >> 9;
        int col = cf * 16 + (lane & 15);
        int k0 = ks * 32 + (lane >> 4) * 8;
        _Float16 h[8], l[8];
#pragma unroll
        for (int i = 0; i < 8; ++i) hsplit(W[(size_t)(k0 + i) * HDIM + col], h[i], l[i]);
        size_t base = (size_t)wsel * 16384 + (size_t)idx * 8;
#pragma unroll
        for (int i = 0; i < 8; ++i) { pkh[base + i] = h[i]; pkl[base + i] = l[i]; }
    }
}

// ---------------- fused layer: ELL-aggregate 64 rows -> LDS(fp16) -> MFMA -> LN -> ReLU ----------------
__global__ __launch_bounds__(256) void layer_fused(const _Float16* __restrict__ h,
                                                   const int* __restrict__ deg,
                                                   const unsigned short* __restrict__ ell,
                                                   const _Float16* __restrict__ Bh,
                                                   const _Float16* __restrict__ Bl,
                                                   const float* __restrict__ bias,
                                                   const float* __restrict__ gamma,
                                                   const float* __restrict__ beta,
                                                   _Float16* __restrict__ out, int nrows) {
    __shared__ _Float16 As[64][LPADH]; // 17.4 KB
    int t = threadIdx.x;
    int blockRow = blockIdx.x * 64;

    // ---- phase 1: gather/aggregate (16 groups of 16 lanes; 4 nodes each) ----
    {
        int g = t >> 4, sub = t & 15;
        const h16x8* h8 = (const h16x8*)h;
        for (int j = 0; j < 4; ++j) {
            int rl = j * 16 + g;
            int node = blockRow + rl;
            h16x8 r;
            if (node < nrows) {
                int dn = deg[node];
                float dd = rsqrtf((float)dn + 1.0f);
                h16x8 v = h8[(size_t)node * 16 + sub];
                float acc[8];
#pragma unroll
                for (int i = 0; i < 8; ++i) acc[i] = dd * (float)v[i];
                int cnt = min(dn, ELLW);
                const unsigned short* row = ell + (size_t)node * ELLW;
                for (int e = 0; e < cnt; e += 4) {
                    uint2 pk = *(const uint2*)(row + e);
                    int s0 = (int)(pk.x & 0xFFFFu);
                    int s1 = (int)(pk.x >> 16);
                    int s2 = (int)(pk.y & 0xFFFFu);
                    int s3 = (int)(pk.y >> 16);
                    bool k1 = e + 1 < cnt, k2 = e + 2 < cnt, k3 = e + 3 < cnt;
                    s1 = k1 ? s1 : s0;
                    s2 = k2 ? s2 : s0;
                    s3 = k3 ? s3 : s0;
                    int d0 = deg[s0];
                    int d1 = deg[s1];
                    int d2 = deg[s2];
                    int d3 = deg[s3];
                    h16x8 u0 = h8[(size_t)s0 * 16 + sub];
                    h16x8 u1 = h8[(size_t)s1 * 16 + sub];
                    h16x8 u2 = h8[(size_t)s2 * 16 + sub];
                    h16x8 u3 = h8[(size_t)s3 * 16 + sub];
                    float w0 = rsqrtf((float)d0 + 1.0f);
                    float w1 = k1 ? rsqrtf((float)d1 + 1.0f) : 0.f;
                    float w2 = k2 ? rsqrtf((float)d2 + 1.0f) : 0.f;
                    float w3 = k3 ? rsqrtf((float)d3 + 1.0f) : 0.f;
#pragma unroll
                    for (int i = 0; i < 8; ++i) {
                        acc[i] += w0 * (float)u0[i];
                        acc[i] += w1 * (float)u1[i];
                        acc[i] += w2 * (float)u2[i];
                        acc[i] += w3 * (float)u3[i];
                    }
                }
#pragma unroll
                for (int i = 0; i < 8; ++i) r[i] = (_Float16)(acc[i] * dd);
            } else {
#pragma unroll
                for (int i = 0; i < 8; ++i) r[i] = (_Float16)0.f;
            }
            *(h16x8*)&As[rl][sub * 8] = r;
        }
    }
    __syncthreads();

    // ---- phase 2: MFMA (f16 A exact, W hi/lo) + bias + two-pass LN + ReLU ----
    int wave = t >> 6, lane = t & 63;
    int lrow = lane & 15, lk = lane >> 4;
    int rowb = blockRow + wave * 16;

    f32x4 acc[8];
#pragma unroll
    for (int cf = 0; cf < 8; ++cf) acc[cf] = (f32x4){0.f, 0.f, 0.f, 0.f};

#pragma unroll
    for (int ks = 0; ks < 4; ++ks) {
        h16x8 a = *(const h16x8*)&As[wave * 16 + lrow][ks * 32 + lk * 8];
        const _Float16* bhp = Bh + (size_t)(ks * 8) * 512 + (size_t)lane * 8;
        const _Float16* blp = Bl + (size_t)(ks * 8) * 512 + (size_t)lane * 8;
#pragma unroll
        for (int cf = 0; cf < 8; ++cf) {
            h16x8 bh = *(const h16x8*)(bhp + (size_t)cf * 512);
            h16x8 bl = *(const h16x8*)(blp + (size_t)cf * 512);
            acc[cf] = __builtin_amdgcn_mfma_f32_16x16x32_f16(a, bh, acc[cf], 0, 0, 0);
            acc[cf] = __builtin_amdgcn_mfma_f32_16x16x32_f16(a, bl, acc[cf], 0, 0, 0);
        }
    }

    float bias_v[8], gam[8], bet[8];
#pragma unroll
    for (int cf = 0; cf < 8; ++cf) {
        bias_v[cf] = bias[cf * 16 + lrow];
        gam[cf] = gamma[cf * 16 + lrow];
        bet[cf] = beta[cf * 16 + lrow];
    }
#pragma unroll
    for (int r = 0; r < 4; ++r) {
        float vv[8];
        float s1 = 0.f;
#pragma unroll
        for (int cf = 0; cf < 8; ++cf) {
            vv[cf] = acc[cf][r] + bias_v[cf];
            s1 += vv[cf];
        }
#pragma unroll
        for (int m = 1; m <= 8; m <<= 1) s1 += __shfl_xor(s1, m);
        float mean = s1 * (1.0f / 128.0f);
        float s2 = 0.f;
        float cc[8];
#pragma unroll
        for (int cf = 0; cf < 8; ++cf) {
            cc[cf] = vv[cf] - mean;
            s2 += cc[cf] * cc[cf];
        }
#pragma unroll
        for (int m = 1; m <= 8; m <<= 1) s2 += __shfl_xor(s2, m);
        float rs = rsqrtf(s2 * (1.0f / 128.0f) + EPS);
        int row = rowb + lk * 4 + r;
        if (row < nrows) {
#pragma unroll
            for (int cf = 0; cf < 8; ++cf) {
                float y = cc[cf] * rs * gam[cf] + bet[cf];
                out[(size_t)row * HDIM + cf * 16 + lrow] = (_Float16)(y > 0.f ? y : 0.f);
            }
        }
    }
}

// ---------------- head: logits = ReLU(A@hW1+hb1)@hW2 + hb2 (A fp16 global) ----------------
__global__ __launch_bounds__(256) void head_mfma(const _Float16* __restrict__ A,
                                                 const _Float16* __restrict__ Bh,
                                                 const _Float16* __restrict__ Bl,
                                                 const float* __restrict__ bias,
                                                 const float* __restrict__ w2,
                                                 const float* __restrict__ b2p,
                                                 float* __restrict__ out, int nrows) {
    int t = threadIdx.x;
    int wave = t >> 6, lane = t & 63;
    int lrow = lane & 15, lk = lane >> 4;
    int rowb = blockIdx.x * 64 + wave * 16;

    f32x4 acc[8];
#pragma unroll
    for (int cf = 0; cf < 8; ++cf) acc[cf] = (f32x4){0.f, 0.f, 0.f, 0.f};

    const _Float16* arow = A + (size_t)(rowb + lrow) * HDIM;
#pragma unroll
    for (int ks = 0; ks < 4; ++ks) {
        h16x8 a = *(const h16x8*)(arow + ks * 32 + lk * 8);
        const _Float16* bhp = Bh + (size_t)(ks * 8) * 512 + (size_t)lane * 8;
        const _Float16* blp = Bl + (size_t)(ks * 8) * 512 + (size_t)lane * 8;
#pragma unroll
        for (int cf = 0; cf < 8; ++cf) {
            h16x8 bh = *(const h16x8*)(bhp + (size_t)cf * 512);
            h16x8 bl = *(const h16x8*)(blp + (size_t)cf * 512);
            acc[cf] = __builtin_amdgcn_mfma_f32_16x16x32_f16(a, bh, acc[cf], 0, 0, 0);
            acc[cf] = __builtin_amdgcn_mfma_f32_16x16x32_f16(a, bl, acc[cf], 0, 0, 0);
        }
    }

    float bias_v[8], w2v[8];
#pragma unroll
    for (int cf = 0; cf < 8; ++cf) {
        bias_v[cf] = bias[cf * 16 + lrow];
        w2v[cf] = w2[cf * 16 + lrow];
    }
    float b2 = b2p[0];
#pragma unroll
    for (int r = 0; r < 4; ++r) {
        float part = 0.f;
#pragma unroll
        for (int cf = 0; cf < 8; ++cf) {
            float y = acc[cf][r] + bias_v[cf];
            y = y > 0.f ? y : 0.f;
            part += y * w2v[cf];
        }
#pragma unroll
        for (int m = 1; m <= 8; m <<= 1) part += __shfl_xor(part, m);
        int row = rowb + lk * 4 + r;
        if (row < nrows && lrow == 0) out[row] = part + b2;
    }
}

extern "C" void kernel_launch(void* const* d_in, const int* in_sizes, int n_in,
                              void* d_out, int out_size, void* d_ws, size_t ws_size,
                              hipStream_t stream) {
    (void)in_sizes; (void)n_in; (void)out_size; (void)ws_size;
    const float* x   = (const float*)d_in[0];
    const int*   ei  = (const int*)d_in[1];
    const float* W0  = (const float*)d_in[2];
    const float* b0  = (const float*)d_in[3];
    const float* g0  = (const float*)d_in[4];
    const float* be0 = (const float*)d_in[5];
    const float* W1  = (const float*)d_in[6];
    const float* b1  = (const float*)d_in[7];
    const float* g1  = (const float*)d_in[8];
    const float* be1 = (const float*)d_in[9];
    const float* W2  = (const float*)d_in[10];
    const float* b2  = (const float*)d_in[11];
    const float* g2  = (const float*)d_in[12];
    const float* be2 = (const float*)d_in[13];
    const float* hW1 = (const float*)d_in[14];
    const float* hb1 = (const float*)d_in[15];
    const float* hW2 = (const float*)d_in[16];
    const float* hb2 = (const float*)d_in[17];
    float* out = (float*)d_out;

    char* w = (char*)d_ws;
    size_t off = 0;
    auto alloc = [&](size_t bytes) -> void* {
        void* p = w + off;
        off += (bytes + 255) & ~(size_t)255;
        return p;
    };
    int*            deg  = (int*)alloc((size_t)N_NODES * 4);
    unsigned short* ell  = (unsigned short*)alloc((size_t)N_NODES * ELLW * 2);
    int*            flag = (int*)alloc(256);
    _Float16*       xh   = (_Float16*)alloc((size_t)N_NODES * HDIM * 2);
    _Float16*       hA   = (_Float16*)alloc((size_t)N_NODES * HDIM * 2);
    _Float16*       hB   = (_Float16*)alloc((size_t)N_NODES * HDIM * 2);
    _Float16*       pkh  = (_Float16*)alloc((size_t)4 * 16384 * 2);
    _Float16*       pkl  = (_Float16*)alloc((size_t)4 * 16384 * 2);

    detect_zero<<<(N_NODES + 255) / 256, 256, 0, stream>>>(ei, flag, deg);
    prep_kernel<<<EDGE_BLKS + CVT_BLKS + PACK_BLKS, 256, 0, stream>>>(
        x, xh, ei, flag, deg, ell, W0, W1, W2, hW1, pkh, pkl);

    int ngb = (N_NODES + 63) / 64; // 782
    // layer 0: xh -> hA
    layer_fused<<<ngb, 256, 0, stream>>>(xh, deg, ell, pkh, pkl, b0, g0, be0, hA, N_NODES);
    // layer 1: hA -> hB
    layer_fused<<<ngb, 256, 0, stream>>>(hA, deg, ell, pkh + (size_t)16384, pkl + (size_t)16384,
                                         b1, g1, be1, hB, N_NODES);
    // layer 2: hB -> hA
    layer_fused<<<ngb, 256, 0, stream>>>(hB, deg, ell, pkh + (size_t)2 * 16384, pkl + (size_t)2 * 16384,
                                         b2, g2, be2, hA, N_NODES);
    // head: ReLU(hA @ hW1 + hb1) @ hW2 + hb2 -> logits
    head_mfma<<<ngb, 256, 0, stream>>>(hA, pkh + (size_t)3 * 16384, pkl + (size_t)3 * 16384,
                                       hb1, hW2, hb2, out, N_NODES);
}

// Round 15
// 162.956 us; speedup vs baseline: 1.0744x; 1.0371x over previous
//
#include <hip/hip_runtime.h>
#include <hip/hip_fp16.h>

#define N_NODES 50000
#define N_EDGES 600000
#define HDIM 128
#define EPS 1e-5f
#define ELLW 64
#define LPADH 136   // fp16 pad: row stride 272B = 17x16B (aligned b128, 8-bank spread)

typedef __attribute__((ext_vector_type(4))) float f32x4;
typedef __attribute__((ext_vector_type(4))) _Float16 h16x4;
typedef __attribute__((ext_vector_type(8))) _Float16 h16x8;

#define EDGE_BLKS ((N_EDGES + 255) / 256)    // 2344, FIRST in grid
#define CVT_BLKS 6250                        // N_NODES*32 float4 / 256
#define PACK_BLKS 32                         // 4 weights x 8 blocks

// ---------------- detect edge dtype + zero deg (one kernel) ----------------
__global__ void detect_zero(const int* __restrict__ ei, int* __restrict__ flag,
                            int* __restrict__ deg) {
    int i = blockIdx.x * 256 + threadIdx.x;
    if (i < N_NODES) deg[i] = 0;
    if (blockIdx.x == 0) {
        __shared__ int nonzero;
        if (threadIdx.x == 0) nonzero = 0;
        __syncthreads();
        int acc = 0;
        for (int k = threadIdx.x; k < 1024; k += 256)
            acc |= ei[2 * k + 1];
        if (acc) atomicOr(&nonzero, 1);
        __syncthreads();
        if (threadIdx.x == 0) *flag = (nonzero == 0) ? 1 : 0;
    }
}

__device__ __forceinline__ int load_idx(const int* __restrict__ ei, int pos, int f) {
    return f ? ei[2 * pos] : ei[pos];
}

// ---------------- f16 hi/lo split ----------------
__device__ __forceinline__ void hsplit(float a, _Float16& hi, _Float16& lo) {
    _Float16 h = (_Float16)a;           // RNE
    hi = h;
    lo = (_Float16)(a - (float)h);
}

// ---------------- fused prep: edge->ELL (first, low-VGPR) | cvt_x | pack_w ----------------
// NOTE: keep ALL branches register-light — kernel-wide VGPR max gates the
// latency-bound edge phase's occupancy (R13 lesson: 48 VGPR -> -3 us total).
__global__ void prep_kernel(const float* __restrict__ x, _Float16* __restrict__ xh,
                            const int* __restrict__ ei, const int* __restrict__ flag,
                            int* __restrict__ deg, unsigned short* __restrict__ ell,
                            const float* __restrict__ W0, const float* __restrict__ W1,
                            const float* __restrict__ W2, const float* __restrict__ W3,
                            _Float16* __restrict__ pkh, _Float16* __restrict__ pkl) {
    int b = blockIdx.x;
    if (b < EDGE_BLKS) {
        int e = b * 256 + threadIdx.x;
        if (e < N_EDGES) {
            int f = *flag;
            int s = load_idx(ei, e, f);
            int d = load_idx(ei, N_EDGES + e, f);
            int pos = atomicAdd(&deg[d], 1);
            if (pos < ELLW) ell[(size_t)d * ELLW + pos] = (unsigned short)s;
        }
    } else if (b < EDGE_BLKS + CVT_BLKS) {
        int idx = (b - EDGE_BLKS) * 256 + threadIdx.x;
        if (idx < N_NODES * 32) {
            float4 v = ((const float4*)x)[idx];
            h16x4 o;
            o[0] = (_Float16)v.x; o[1] = (_Float16)v.y;
            o[2] = (_Float16)v.z; o[3] = (_Float16)v.w;
            ((h16x4*)xh)[idx] = o;
        }
    } else {
        int pb = b - EDGE_BLKS - CVT_BLKS;   // 0..31
        int wsel = pb >> 3;
        const float* W = (wsel == 0) ? W0 : (wsel == 1) ? W1 : (wsel == 2) ? W2 : W3;
        int idx = (pb & 7) * 256 + threadIdx.x; // 0..2047
        int lane = idx & 63;
        int cf = (idx >> 6) & 7;
        int ks = idx >> 9;
        int col = cf * 16 + (lane & 15);
        int k0 = ks * 32 + (lane >> 4) * 8;
        _Float16 h[8], l[8];
#pragma unroll
        for (int i = 0; i < 8; ++i) hsplit(W[(size_t)(k0 + i) * HDIM + col], h[i], l[i]);
        size_t base = (size_t)wsel * 16384 + (size_t)idx * 8;
#pragma unroll
        for (int i = 0; i < 8; ++i) { pkh[base + i] = h[i]; pkl[base + i] = l[i]; }
    }
}

// ---------------- fused layer: ELL-aggregate -> LDS fp16 -> MFMA -> LN -> ReLU ----------------
// HEAD=false: write fp16 activations to `out`
// HEAD=true (layer 2): write activations to As, then in-block head
//   logits = ReLU(act @ hW1 + hb1) @ hW2 + hb2  (each wave owns its 16 rows)
template <bool HEAD>
__global__ __launch_bounds__(256) void layer_fused(const _Float16* __restrict__ h,
                                                   const int* __restrict__ deg,
                                                   const unsigned short* __restrict__ ell,
                                                   const _Float16* __restrict__ Bh,
                                                   const _Float16* __restrict__ Bl,
                                                   const float* __restrict__ bias,
                                                   const float* __restrict__ gamma,
                                                   const float* __restrict__ beta,
                                                   _Float16* __restrict__ out,
                                                   const _Float16* __restrict__ Hh,
                                                   const _Float16* __restrict__ Hl,
                                                   const float* __restrict__ hb1,
                                                   const float* __restrict__ hw2,
                                                   const float* __restrict__ hb2,
                                                   float* __restrict__ logits,
                                                   int nrows) {
    __shared__ _Float16 As[64][LPADH]; // 17.4 KB
    int t = threadIdx.x;
    int blockRow = blockIdx.x * 64;

    // ---- phase 1: gather/aggregate (16 groups of 16 lanes; 4 nodes each) ----
    {
        int g = t >> 4, sub = t & 15;
        const h16x8* h8 = (const h16x8*)h;
        for (int j = 0; j < 4; ++j) {
            int rl = j * 16 + g;
            int node = blockRow + rl;
            h16x8 r;
            if (node < nrows) {
                int dn = deg[node];
                float dd = rsqrtf((float)dn + 1.0f);
                h16x8 v = h8[(size_t)node * 16 + sub];
                float acc[8];
#pragma unroll
                for (int i = 0; i < 8; ++i) acc[i] = dd * (float)v[i];
                int cnt = min(dn, ELLW);
                const unsigned short* row = ell + (size_t)node * ELLW;
                for (int e = 0; e < cnt; e += 4) {
                    uint2 pk = *(const uint2*)(row + e);
                    int s0 = (int)(pk.x & 0xFFFFu);
                    int s1 = (int)(pk.x >> 16);
                    int s2 = (int)(pk.y & 0xFFFFu);
                    int s3 = (int)(pk.y >> 16);
                    bool k1 = e + 1 < cnt, k2 = e + 2 < cnt, k3 = e + 3 < cnt;
                    s1 = k1 ? s1 : s0;
                    s2 = k2 ? s2 : s0;
                    s3 = k3 ? s3 : s0;
                    int d0 = deg[s0];
                    int d1 = deg[s1];
                    int d2 = deg[s2];
                    int d3 = deg[s3];
                    h16x8 u0 = h8[(size_t)s0 * 16 + sub];
                    h16x8 u1 = h8[(size_t)s1 * 16 + sub];
                    h16x8 u2 = h8[(size_t)s2 * 16 + sub];
                    h16x8 u3 = h8[(size_t)s3 * 16 + sub];
                    float w0 = rsqrtf((float)d0 + 1.0f);
                    float w1 = k1 ? rsqrtf((float)d1 + 1.0f) : 0.f;
                    float w2 = k2 ? rsqrtf((float)d2 + 1.0f) : 0.f;
                    float w3 = k3 ? rsqrtf((float)d3 + 1.0f) : 0.f;
#pragma unroll
                    for (int i = 0; i < 8; ++i) {
                        acc[i] += w0 * (float)u0[i];
                        acc[i] += w1 * (float)u1[i];
                        acc[i] += w2 * (float)u2[i];
                        acc[i] += w3 * (float)u3[i];
                    }
                }
#pragma unroll
                for (int i = 0; i < 8; ++i) r[i] = (_Float16)(acc[i] * dd);
            } else {
#pragma unroll
                for (int i = 0; i < 8; ++i) r[i] = (_Float16)0.f;
            }
            *(h16x8*)&As[rl][sub * 8] = r;
        }
    }
    __syncthreads();

    // ---- phase 2: MFMA (f16 A exact, W hi/lo) + bias + two-pass LN + ReLU ----
    int wave = t >> 6, lane = t & 63;
    int lrow = lane & 15, lk = lane >> 4;
    int rowb = blockRow + wave * 16;

    f32x4 acc[8];
#pragma unroll
    for (int cf = 0; cf < 8; ++cf) acc[cf] = (f32x4){0.f, 0.f, 0.f, 0.f};

#pragma unroll
    for (int ks = 0; ks < 4; ++ks) {
        h16x8 a = *(const h16x8*)&As[wave * 16 + lrow][ks * 32 + lk * 8];
        const _Float16* bhp = Bh + (size_t)(ks * 8) * 512 + (size_t)lane * 8;
        const _Float16* blp = Bl + (size_t)(ks * 8) * 512 + (size_t)lane * 8;
#pragma unroll
        for (int cf = 0; cf < 8; ++cf) {
            h16x8 bh = *(const h16x8*)(bhp + (size_t)cf * 512);
            h16x8 bl = *(const h16x8*)(blp + (size_t)cf * 512);
            acc[cf] = __builtin_amdgcn_mfma_f32_16x16x32_f16(a, bh, acc[cf], 0, 0, 0);
            acc[cf] = __builtin_amdgcn_mfma_f32_16x16x32_f16(a, bl, acc[cf], 0, 0, 0);
        }
    }

    float bias_v[8], gam[8], bet[8];
#pragma unroll
    for (int cf = 0; cf < 8; ++cf) {
        bias_v[cf] = bias[cf * 16 + lrow];
        gam[cf] = gamma[cf * 16 + lrow];
        bet[cf] = beta[cf * 16 + lrow];
    }
#pragma unroll
    for (int r = 0; r < 4; ++r) {
        float vv[8];
        float s1 = 0.f;
#pragma unroll
        for (int cf = 0; cf < 8; ++cf) {
            vv[cf] = acc[cf][r] + bias_v[cf];
            s1 += vv[cf];
        }
#pragma unroll
        for (int m = 1; m <= 8; m <<= 1) s1 += __shfl_xor(s1, m);
        float mean = s1 * (1.0f / 128.0f);
        float s2 = 0.f;
        float cc[8];
#pragma unroll
        for (int cf = 0; cf < 8; ++cf) {
            cc[cf] = vv[cf] - mean;
            s2 += cc[cf] * cc[cf];
        }
#pragma unroll
        for (int m = 1; m <= 8; m <<= 1) s2 += __shfl_xor(s2, m);
        float rs = rsqrtf(s2 * (1.0f / 128.0f) + EPS);
        int row = rowb + lk * 4 + r;
        if (HEAD) {
            // write activations back into the wave's own 16-row As slice
#pragma unroll
            for (int cf = 0; cf < 8; ++cf) {
                float y = cc[cf] * rs * gam[cf] + bet[cf];
                As[wave * 16 + lk * 4 + r][cf * 16 + lrow] = (_Float16)(y > 0.f ? y : 0.f);
            }
        } else if (row < nrows) {
#pragma unroll
            for (int cf = 0; cf < 8; ++cf) {
                float y = cc[cf] * rs * gam[cf] + bet[cf];
                out[(size_t)row * HDIM + cf * 16 + lrow] = (_Float16)(y > 0.f ? y : 0.f);
            }
        }
    }

    if (HEAD) {
        __syncthreads();  // cross-lane As visibility within wave slices
        // ---- phase 3: logits = ReLU(As @ hW1 + hb1) @ hW2 + hb2 ----
        f32x4 acc2[8];
#pragma unroll
        for (int cf = 0; cf < 8; ++cf) acc2[cf] = (f32x4){0.f, 0.f, 0.f, 0.f};
#pragma unroll
        for (int ks = 0; ks < 4; ++ks) {
            h16x8 a = *(const h16x8*)&As[wave * 16 + lrow][ks * 32 + lk * 8];
            const _Float16* bhp = Hh + (size_t)(ks * 8) * 512 + (size_t)lane * 8;
            const _Float16* blp = Hl + (size_t)(ks * 8) * 512 + (size_t)lane * 8;
#pragma unroll
            for (int cf = 0; cf < 8; ++cf) {
                h16x8 bh = *(const h16x8*)(bhp + (size_t)cf * 512);
                h16x8 bl = *(const h16x8*)(blp + (size_t)cf * 512);
                acc2[cf] = __builtin_amdgcn_mfma_f32_16x16x32_f16(a, bh, acc2[cf], 0, 0, 0);
                acc2[cf] = __builtin_amdgcn_mfma_f32_16x16x32_f16(a, bl, acc2[cf], 0, 0, 0);
            }
        }
        float hb_v[8], w2v[8];
#pragma unroll
        for (int cf = 0; cf < 8; ++cf) {
            hb_v[cf] = hb1[cf * 16 + lrow];
            w2v[cf] = hw2[cf * 16 + lrow];
        }
        float b2 = hb2[0];
#pragma unroll
        for (int r = 0; r < 4; ++r) {
            float part = 0.f;
#pragma unroll
            for (int cf = 0; cf < 8; ++cf) {
                float y = acc2[cf][r] + hb_v[cf];
                y = y > 0.f ? y : 0.f;
                part += y * w2v[cf];
            }
#pragma unroll
            for (int m = 1; m <= 8; m <<= 1) part += __shfl_xor(part, m);
            int row = rowb + lk * 4 + r;
            if (row < nrows && lrow == 0) logits[row] = part + b2;
        }
    }
}

extern "C" void kernel_launch(void* const* d_in, const int* in_sizes, int n_in,
                              void* d_out, int out_size, void* d_ws, size_t ws_size,
                              hipStream_t stream) {
    (void)in_sizes; (void)n_in; (void)out_size; (void)ws_size;
    const float* x   = (const float*)d_in[0];
    const int*   ei  = (const int*)d_in[1];
    const float* W0  = (const float*)d_in[2];
    const float* b0  = (const float*)d_in[3];
    const float* g0  = (const float*)d_in[4];
    const float* be0 = (const float*)d_in[5];
    const float* W1  = (const float*)d_in[6];
    const float* b1  = (const float*)d_in[7];
    const float* g1  = (const float*)d_in[8];
    const float* be1 = (const float*)d_in[9];
    const float* W2  = (const float*)d_in[10];
    const float* b2  = (const float*)d_in[11];
    const float* g2  = (const float*)d_in[12];
    const float* be2 = (const float*)d_in[13];
    const float* hW1 = (const float*)d_in[14];
    const float* hb1 = (const float*)d_in[15];
    const float* hW2 = (const float*)d_in[16];
    const float* hb2 = (const float*)d_in[17];
    float* out = (float*)d_out;

    char* w = (char*)d_ws;
    size_t off = 0;
    auto alloc = [&](size_t bytes) -> void* {
        void* p = w + off;
        off += (bytes + 255) & ~(size_t)255;
        return p;
    };
    int*            deg  = (int*)alloc((size_t)N_NODES * 4);
    unsigned short* ell  = (unsigned short*)alloc((size_t)N_NODES * ELLW * 2);
    int*            flag = (int*)alloc(256);
    _Float16*       xh   = (_Float16*)alloc((size_t)N_NODES * HDIM * 2);
    _Float16*       hA   = (_Float16*)alloc((size_t)N_NODES * HDIM * 2);
    _Float16*       hB   = (_Float16*)alloc((size_t)N_NODES * HDIM * 2);
    _Float16*       pkh  = (_Float16*)alloc((size_t)4 * 16384 * 2);
    _Float16*       pkl  = (_Float16*)alloc((size_t)4 * 16384 * 2);

    detect_zero<<<(N_NODES + 255) / 256, 256, 0, stream>>>(ei, flag, deg);
    prep_kernel<<<EDGE_BLKS + CVT_BLKS + PACK_BLKS, 256, 0, stream>>>(
        x, xh, ei, flag, deg, ell, W0, W1, W2, hW1, pkh, pkl);

    int ngb = (N_NODES + 63) / 64; // 782
    // layer 0: xh -> hA
    layer_fused<false><<<ngb, 256, 0, stream>>>(xh, deg, ell, pkh, pkl, b0, g0, be0, hA,
                                                nullptr, nullptr, nullptr, nullptr, nullptr,
                                                nullptr, N_NODES);
    // layer 1: hA -> hB
    layer_fused<false><<<ngb, 256, 0, stream>>>(hA, deg, ell,
                                                pkh + (size_t)16384, pkl + (size_t)16384,
                                                b1, g1, be1, hB,
                                                nullptr, nullptr, nullptr, nullptr, nullptr,
                                                nullptr, N_NODES);
    // layer 2 + head: hB -> logits  (W2 = pkh+2*16384, hW1 = pkh+3*16384)
    layer_fused<true><<<ngb, 256, 0, stream>>>(hB, deg, ell,
                                               pkh + (size_t)2 * 16384, pkl + (size_t)2 * 16384,
                                               b2, g2, be2, nullptr,
                                               pkh + (size_t)3 * 16384, pkl + (size_t)3 * 16384,
                                               hb1, hW2, hb2, out, N_NODES);
}